// Round 1
// baseline (522.703 us; speedup 1.0000x reference)
//
#include <hip/hip_runtime.h>
#include <hip/hip_bf16.h>

// ---- constants for this problem ----
#define BB 4
#define TT 2048
#define DD 1024
#define HH 16
#define HD 64
#define FF 2048

typedef unsigned short u16;
typedef __bf16 bf16x8 __attribute__((ext_vector_type(8)));
typedef float f32x4 __attribute__((ext_vector_type(4)));
typedef unsigned short u16x8 __attribute__((ext_vector_type(8)));
typedef unsigned short u16x4 __attribute__((ext_vector_type(4)));

__device__ __forceinline__ u16 f2bf(float f) {
    unsigned u = __builtin_bit_cast(unsigned, f);
    unsigned r = (u + 0x7fffu + ((u >> 16) & 1u)) >> 16;
    return (u16)r;
}

// ---------------- conversion kernels ----------------
__global__ __launch_bounds__(256) void convert_x(const float* __restrict__ in, u16* __restrict__ out, int n8) {
    int i = blockIdx.x * 256 + threadIdx.x;
    if (i >= n8) return;
    const float4* p = (const float4*)in + (size_t)i * 2;
    float4 a = p[0], b = p[1];
    u16x8 o;
    o[0] = f2bf(a.x); o[1] = f2bf(a.y); o[2] = f2bf(a.z); o[3] = f2bf(a.w);
    o[4] = f2bf(b.x); o[5] = f2bf(b.y); o[6] = f2bf(b.z); o[7] = f2bf(b.w);
    ((u16x8*)out)[i] = o;
}

// out[c][r] = bf16(in[r][c]) ; grid (C/32, R/32), block 256
__global__ __launch_bounds__(256) void transpose_conv(const float* __restrict__ in, u16* __restrict__ out, int R, int C) {
    __shared__ float tile[32][33];
    const int c0 = blockIdx.x * 32, r0 = blockIdx.y * 32;
    const int tx = threadIdx.x & 31, ty = threadIdx.x >> 5;
#pragma unroll
    for (int j = 0; j < 4; ++j) tile[ty + j * 8][tx] = in[(size_t)(r0 + ty + j * 8) * C + c0 + tx];
    __syncthreads();
#pragma unroll
    for (int j = 0; j < 4; ++j) out[(size_t)(c0 + ty + j * 8) * R + r0 + tx] = f2bf(tile[tx][ty + j * 8]);
}

// per (w,h): transpose [1024,64] -> [64,1024]; grid (2, 32, 48)
__global__ __launch_bounds__(256) void qkv_transpose(const float* __restrict__ Wq, const float* __restrict__ Wk,
                                                     const float* __restrict__ Wv, u16* __restrict__ out) {
    __shared__ float tile[32][33];
    const int z = blockIdx.z, w = z >> 4, h = z & 15;
    const float* in = (w == 0 ? Wq : (w == 1 ? Wk : Wv)) + (size_t)h * (DD * HD);
    u16* op = out + (size_t)(w * 1024 + h * 64) * DD;
    const int c0 = blockIdx.x * 32, r0 = blockIdx.y * 32;
    const int tx = threadIdx.x & 31, ty = threadIdx.x >> 5;
#pragma unroll
    for (int j = 0; j < 4; ++j) tile[ty + j * 8][tx] = in[(size_t)(r0 + ty + j * 8) * HD + c0 + tx];
    __syncthreads();
#pragma unroll
    for (int j = 0; j < 4; ++j) op[(size_t)(c0 + ty + j * 8) * DD + r0 + tx] = f2bf(tile[tx][ty + j * 8]);
}

__global__ __launch_bounds__(256) void pack_bias(const float* __restrict__ bq, const float* __restrict__ bk,
                                                 const float* __restrict__ bv, float* __restrict__ out) {
    int i = blockIdx.x * 256 + threadIdx.x;
    if (i < 3072) {
        const float* s = i < 1024 ? bq : (i < 2048 ? bk : bv);
        out[i] = s[i & 1023];
    }
}

// ---------------- GEMM: C[M,N] = A[M,K] * Bt[N,K]^T (bf16 in, fp32 acc) ----------------
// EPI 0: qkv scatter (bf16)   1: +bias+res -> f32   2: relu(+bias) -> bf16   3: same as 1
#define GBM 128
#define GBN 128
#define GBK 64

template <int EPI>
__global__ __launch_bounds__(256) void gemm_bt(const u16* __restrict__ A, const u16* __restrict__ Bt,
                                               const float* __restrict__ bias, const float* __restrict__ res,
                                               void* __restrict__ outp, int M, int N, int K) {
    __shared__ __align__(16) u16 sA[GBM * GBK];
    __shared__ __align__(16) u16 sB[GBN * GBK];
    const int t = threadIdx.x;
    const int lane = t & 63, wv = t >> 6;
    const int wm = (wv >> 1) * 64, wn = (wv & 1) * 64;
    const int lq = lane & 15, lk8 = (lane >> 4) * 8;
    const int m0 = blockIdx.y * GBM, n0 = blockIdx.x * GBN;

    f32x4 acc[4][4];
#pragma unroll
    for (int i = 0; i < 4; ++i)
#pragma unroll
        for (int j = 0; j < 4; ++j) acc[i][j] = (f32x4){0.f, 0.f, 0.f, 0.f};

    for (int k0 = 0; k0 < K; k0 += GBK) {
#pragma unroll
        for (int it = 0; it < 4; ++it) {
            int i = t + it * 256;
            int row = i >> 3, cc = (i & 7) * 8;
            u16x8 va = *(const u16x8*)(A + (size_t)(m0 + row) * K + k0 + cc);
            u16x8 vb = *(const u16x8*)(Bt + (size_t)(n0 + row) * K + k0 + cc);
            int by = (row * 128 + cc * 2) ^ ((row & 7) << 4);
            *(u16x8*)((char*)sA + by) = va;
            *(u16x8*)((char*)sB + by) = vb;
        }
        __syncthreads();
#pragma unroll
        for (int kk = 0; kk < 2; ++kk) {
            bf16x8 af[4], bfr[4];
#pragma unroll
            for (int mf = 0; mf < 4; ++mf) {
                int row = wm + mf * 16 + lq;
                int by = (row * 128 + kk * 64 + lk8 * 2) ^ ((row & 7) << 4);
                af[mf] = *(const bf16x8*)((const char*)sA + by);
            }
#pragma unroll
            for (int nf = 0; nf < 4; ++nf) {
                int row = wn + nf * 16 + lq;
                int by = (row * 128 + kk * 64 + lk8 * 2) ^ ((row & 7) << 4);
                bfr[nf] = *(const bf16x8*)((const char*)sB + by);
            }
#pragma unroll
            for (int mf = 0; mf < 4; ++mf)
#pragma unroll
                for (int nf = 0; nf < 4; ++nf)
                    acc[mf][nf] = __builtin_amdgcn_mfma_f32_16x16x32_bf16(af[mf], bfr[nf], acc[mf][nf], 0, 0, 0);
        }
        __syncthreads();
    }

    const int rbase = (lane >> 4) * 4;
#pragma unroll
    for (int mf = 0; mf < 4; ++mf) {
#pragma unroll
        for (int nf = 0; nf < 4; ++nf) {
            int gn = n0 + wn + nf * 16 + lq;
            float bv = bias[gn];
#pragma unroll
            for (int r = 0; r < 4; ++r) {
                int gm = m0 + wm + mf * 16 + rbase + r;
                float val = acc[mf][nf][r] + bv;
                if (EPI == 0) {
                    int which = gn >> 10, hh = (gn >> 6) & 15, hd = gn & 63;
                    int b = gm >> 11, tt2 = gm & 2047;
                    size_t off = (size_t)which * ((size_t)BB * HH * TT * HD) +
                                 ((size_t)(b * HH + hh) * TT + tt2) * HD + hd;
                    ((u16*)outp)[off] = f2bf(val);
                } else if (EPI == 2) {
                    ((u16*)outp)[(size_t)gm * N + gn] = f2bf(val > 0.f ? val : 0.f);
                } else {
                    ((float*)outp)[(size_t)gm * N + gn] = val + res[(size_t)gm * N + gn];
                }
            }
        }
    }
}

// ---------------- flash attention ----------------
// qkv layout: [3][B][H][T][HD] bf16. out ctx: [B][T][D] bf16.
// grid (T/64, B*H), block 256 (4 waves x 16 q-rows), KV tile = 64
__global__ __launch_bounds__(256) void attn_kernel(const u16* __restrict__ qkv, u16* __restrict__ ctx) {
    const int t = threadIdx.x, wv = t >> 6, lane = t & 63;
    const int lq = lane & 15, lk8 = (lane >> 4) * 8;
    const int qt = blockIdx.x, bh = blockIdx.y;
    const size_t WSTR = (size_t)BB * HH * TT * HD;
    const u16* qp = qkv + (size_t)bh * TT * HD;
    const u16* kp = qp + WSTR;
    const u16* vp = qp + 2 * WSTR;
    const int qr = qt * 64 + wv * 16;

    __shared__ __align__(16) u16 sK[64 * 64];
    __shared__ __align__(16) u16 sVt[64 * 64];
    __shared__ __align__(16) u16 sP[4][16 * 64];

    const bf16x8 qf0 = *(const bf16x8*)(qp + (size_t)(qr + lq) * HD + lk8);
    const bf16x8 qf1 = *(const bf16x8*)(qp + (size_t)(qr + lq) * HD + lk8 + 32);

    float mrun = -INFINITY, lsum = 0.f;
    f32x4 o[4];
#pragma unroll
    for (int i = 0; i < 4; ++i) o[i] = (f32x4){0.f, 0.f, 0.f, 0.f};

    for (int kt = 0; kt < TT / 64; ++kt) {
        const int kb = kt * 64;
        __syncthreads();
        // stage K (swizzled rows) and V^T (transposed, swizzled)
#pragma unroll
        for (int it = 0; it < 2; ++it) {
            int i = t + it * 256;
            int row = i >> 3, cc = (i & 7) * 8;
            u16x8 kv = *(const u16x8*)(kp + (size_t)(kb + row) * HD + cc);
            int by = (row * 128 + cc * 2) ^ ((row & 7) << 4);
            *(u16x8*)((char*)sK + by) = kv;
            u16x8 vvv = *(const u16x8*)(vp + (size_t)(kb + row) * HD + cc);
#pragma unroll
            for (int j = 0; j < 8; ++j) {
                int d = cc + j;
                int vby = (d * 128 + row * 2) ^ ((d & 7) << 4);
                *(u16*)((char*)sVt + vby) = vvv[j];
            }
        }
        __syncthreads();

        // S^T = K * Q^T  (lane owns q = lq; rows = keys)
        f32x4 s[4];
#pragma unroll
        for (int st = 0; st < 4; ++st) {
            int krow = st * 16 + lq;
            int sw = (krow & 7) << 4;
            bf16x8 kf0 = *(const bf16x8*)((const char*)sK + ((krow * 128 + lk8 * 2) ^ sw));
            bf16x8 kf1 = *(const bf16x8*)((const char*)sK + ((krow * 128 + 64 + lk8 * 2) ^ sw));
            f32x4 z = (f32x4){0.f, 0.f, 0.f, 0.f};
            z = __builtin_amdgcn_mfma_f32_16x16x32_bf16(kf0, qf0, z, 0, 0, 0);
            z = __builtin_amdgcn_mfma_f32_16x16x32_bf16(kf1, qf1, z, 0, 0, 0);
            s[st] = z * 0.125f;
        }
        // online softmax (per lane: 16 scores for q=lq; row group = lanes {lq, lq+16, lq+32, lq+48})
        float tmax = -INFINITY;
#pragma unroll
        for (int st = 0; st < 4; ++st)
#pragma unroll
            for (int r = 0; r < 4; ++r) tmax = fmaxf(tmax, s[st][r]);
        tmax = fmaxf(tmax, __shfl_xor(tmax, 16));
        tmax = fmaxf(tmax, __shfl_xor(tmax, 32));
        float mnew = fmaxf(mrun, tmax);
        float alpha = expf(mrun - mnew);
        float psum = 0.f;
#pragma unroll
        for (int st = 0; st < 4; ++st)
#pragma unroll
            for (int r = 0; r < 4; ++r) {
                float p = expf(s[st][r] - mnew);
                s[st][r] = p;
                psum += p;
            }
        psum += __shfl_xor(psum, 16);
        psum += __shfl_xor(psum, 32);
        lsum = lsum * alpha + psum;
        mrun = mnew;
#pragma unroll
        for (int nd = 0; nd < 4; ++nd) o[nd] *= alpha;
        // write P (bf16) to per-wave LDS: [16 q][64 k], swizzled
#pragma unroll
        for (int st = 0; st < 4; ++st) {
            u16x4 pk;
#pragma unroll
            for (int r = 0; r < 4; ++r) pk[r] = f2bf(s[st][r]);
            int col = st * 16 + (lane >> 4) * 4;
            int by = (lq * 128 + col * 2) ^ ((lq & 7) << 4);
            *(u16x4*)((char*)sP[wv] + by) = pk;
        }
        __syncthreads();
        // O^T += V^T * P^T  (lane owns q = lq in cols)
#pragma unroll
        for (int nd = 0; nd < 4; ++nd) {
            int drow = nd * 16 + lq;
            int vsw = (drow & 7) << 4;
            bf16x8 vf0 = *(const bf16x8*)((const char*)sVt + ((drow * 128 + lk8 * 2) ^ vsw));
            bf16x8 vf1 = *(const bf16x8*)((const char*)sVt + ((drow * 128 + 64 + lk8 * 2) ^ vsw));
            int psw = (lq & 7) << 4;
            bf16x8 pf0 = *(const bf16x8*)((const char*)sP[wv] + ((lq * 128 + lk8 * 2) ^ psw));
            bf16x8 pf1 = *(const bf16x8*)((const char*)sP[wv] + ((lq * 128 + 64 + lk8 * 2) ^ psw));
            o[nd] = __builtin_amdgcn_mfma_f32_16x16x32_bf16(vf0, pf0, o[nd], 0, 0, 0);
            o[nd] = __builtin_amdgcn_mfma_f32_16x16x32_bf16(vf1, pf1, o[nd], 0, 0, 0);
        }
    }

    const float inv = 1.f / lsum;
    const int b = bh >> 4, h = bh & 15;
    const size_t orow = ((size_t)b * TT + (qr + lq)) * DD + h * HD;
    const int rbase = (lane >> 4) * 4;
#pragma unroll
    for (int nd = 0; nd < 4; ++nd) {
        u16x4 ov;
#pragma unroll
        for (int r = 0; r < 4; ++r) ov[r] = f2bf(o[nd][r] * inv);
        *(u16x4*)(ctx + orow + nd * 16 + rbase) = ov;
    }
}

// ---------------- layernorm (one block per row of 1024) ----------------
template <bool WB>
__global__ __launch_bounds__(256) void ln_kernel(const float* __restrict__ y, const float* __restrict__ g,
                                                 const float* __restrict__ b, float* __restrict__ of,
                                                 u16* __restrict__ ob) {
    const int row = blockIdx.x, t = threadIdx.x;
    const float4 v = ((const float4*)(y + (size_t)row * DD))[t];
    float s = v.x + v.y + v.z + v.w;
    float q = v.x * v.x + v.y * v.y + v.z * v.z + v.w * v.w;
#pragma unroll
    for (int m = 1; m < 64; m <<= 1) {
        s += __shfl_xor(s, m);
        q += __shfl_xor(q, m);
    }
    __shared__ float red[8];
    const int wv = t >> 6, ln = t & 63;
    if (ln == 0) {
        red[wv] = s;
        red[4 + wv] = q;
    }
    __syncthreads();
    s = red[0] + red[1] + red[2] + red[3];
    q = red[4] + red[5] + red[6] + red[7];
    const float mu = s * (1.f / DD);
    const float var = q * (1.f / DD) - mu * mu;
    const float rstd = rsqrtf(var + 1e-5f);
    const float4 gg = ((const float4*)g)[t];
    const float4 bb = ((const float4*)b)[t];
    float4 o;
    o.x = (v.x - mu) * rstd * gg.x + bb.x;
    o.y = (v.y - mu) * rstd * gg.y + bb.y;
    o.z = (v.z - mu) * rstd * gg.z + bb.z;
    o.w = (v.w - mu) * rstd * gg.w + bb.w;
    ((float4*)(of + (size_t)row * DD))[t] = o;
    if (WB) {
        u16x4 u;
        u[0] = f2bf(o.x); u[1] = f2bf(o.y); u[2] = f2bf(o.z); u[3] = f2bf(o.w);
        *(u16x4*)(ob + (size_t)row * DD + t * 4) = u;
    }
}

// ---------------- launch ----------------
extern "C" void kernel_launch(void* const* d_in, const int* in_sizes, int n_in,
                              void* d_out, int out_size, void* d_ws, size_t ws_size,
                              hipStream_t stream) {
    const float* x   = (const float*)d_in[0];
    const float* Wq  = (const float*)d_in[1];
    const float* bq  = (const float*)d_in[2];
    const float* Wk  = (const float*)d_in[3];
    const float* bk  = (const float*)d_in[4];
    const float* Wv  = (const float*)d_in[5];
    const float* bv  = (const float*)d_in[6];
    const float* Wo  = (const float*)d_in[7];
    const float* bo  = (const float*)d_in[8];
    const float* g1  = (const float*)d_in[9];
    const float* be1 = (const float*)d_in[10];
    const float* W1  = (const float*)d_in[11];
    const float* b1  = (const float*)d_in[12];
    const float* W2  = (const float*)d_in[13];
    const float* b2  = (const float*)d_in[14];
    const float* g2  = (const float*)d_in[15];
    const float* be2 = (const float*)d_in[16];
    float* out = (float*)d_out;

    char* ws = (char*)d_ws;
    u16*   xb    = (u16*)(ws + 0);           // 16 MB   (reused as ctx)
    u16*   wqkvt = (u16*)(ws + 16777216);    // 6 MB
    u16*   wot   = (u16*)(ws + 23068672);    // 2 MB
    u16*   w1t   = (u16*)(ws + 25165824);    // 4 MB
    u16*   w2t   = (u16*)(ws + 29360128);    // 4 MB
    float* bqkv  = (float*)(ws + 33554432);  // 12 KB
    u16*   qkvb  = (u16*)(ws + 33566720);    // 48 MB  (reused as h)
    float* y1    = (float*)(ws + 83898368);  // 32 MB  (reused as y2)
    float* x1f   = (float*)(ws + 117452800); // 32 MB
    u16*   x1b   = (u16*)(ws + 151007232);   // 16 MB
    u16*   ctx   = xb;
    u16*   hbuf  = qkvb;
    float* y2    = y1;

    const int M = BB * TT;  // 8192

    // conversions
    convert_x<<<dim3((M * DD / 8 + 255) / 256), 256, 0, stream>>>(x, xb, M * DD / 8);
    qkv_transpose<<<dim3(2, 32, 48), 256, 0, stream>>>(Wq, Wk, Wv, wqkvt);
    transpose_conv<<<dim3(32, 32), 256, 0, stream>>>(Wo, wot, DD, DD);
    transpose_conv<<<dim3(64, 32), 256, 0, stream>>>(W1, w1t, DD, FF);
    transpose_conv<<<dim3(32, 64), 256, 0, stream>>>(W2, w2t, FF, DD);
    pack_bias<<<dim3(12), 256, 0, stream>>>(bq, bk, bv, bqkv);

    // QKV projection
    gemm_bt<0><<<dim3(3 * DD / GBN, M / GBM), 256, 0, stream>>>(xb, wqkvt, bqkv, nullptr, qkvb, M, 3 * DD, DD);
    // attention
    attn_kernel<<<dim3(TT / 64, BB * HH), 256, 0, stream>>>(qkvb, ctx);
    // output projection + bias + residual(x)
    gemm_bt<1><<<dim3(DD / GBN, M / GBM), 256, 0, stream>>>(ctx, wot, bo, x, y1, M, DD, DD);
    // LN1 -> x1f (f32) + x1b (bf16)
    ln_kernel<true><<<dim3(M), 256, 0, stream>>>(y1, g1, be1, x1f, x1b);
    // FFN1 (relu)
    gemm_bt<2><<<dim3(FF / GBN, M / GBM), 256, 0, stream>>>(x1b, w1t, b1, nullptr, hbuf, M, FF, DD);
    // FFN2 + bias + residual(x1f)
    gemm_bt<3><<<dim3(DD / GBN, M / GBM), 256, 0, stream>>>(hbuf, w2t, b2, x1f, y2, M, DD, FF);
    // LN2 -> out
    ln_kernel<false><<<dim3(M), 256, 0, stream>>>(y2, g2, be2, out, nullptr);
}

// Round 2
// 404.843 us; speedup vs baseline: 1.2911x; 1.2911x over previous
//
#include <hip/hip_runtime.h>
#include <hip/hip_bf16.h>

// ---- constants for this problem ----
#define BB 4
#define TT 2048
#define DD 1024
#define HH 16
#define HD 64
#define FF 2048
// Q pre-scale: 1/sqrt(64) * log2(e)  (softmax runs in exp2 domain)
#define QSCL 0.1803368801111204f

typedef unsigned short u16;
typedef __bf16 bf16x8 __attribute__((ext_vector_type(8)));
typedef float f32x4 __attribute__((ext_vector_type(4)));
typedef unsigned short u16x8 __attribute__((ext_vector_type(8)));
typedef unsigned short u16x4 __attribute__((ext_vector_type(4)));

__device__ __forceinline__ u16 f2bf(float f) {
    unsigned u = __builtin_bit_cast(unsigned, f);
    unsigned r = (u + 0x7fffu + ((u >> 16) & 1u)) >> 16;
    return (u16)r;
}

// ---------------- conversion kernels ----------------
__global__ __launch_bounds__(256) void convert_x(const float* __restrict__ in, u16* __restrict__ out, int n8) {
    int i = blockIdx.x * 256 + threadIdx.x;
    if (i >= n8) return;
    const float4* p = (const float4*)in + (size_t)i * 2;
    float4 a = p[0], b = p[1];
    u16x8 o;
    o[0] = f2bf(a.x); o[1] = f2bf(a.y); o[2] = f2bf(a.z); o[3] = f2bf(a.w);
    o[4] = f2bf(b.x); o[5] = f2bf(b.y); o[6] = f2bf(b.z); o[7] = f2bf(b.w);
    ((u16x8*)out)[i] = o;
}

// out[c][r] = bf16(in[r][c]) ; grid (C/32, R/32), block 256
__global__ __launch_bounds__(256) void transpose_conv(const float* __restrict__ in, u16* __restrict__ out, int R, int C) {
    __shared__ float tile[32][33];
    const int c0 = blockIdx.x * 32, r0 = blockIdx.y * 32;
    const int tx = threadIdx.x & 31, ty = threadIdx.x >> 5;
#pragma unroll
    for (int j = 0; j < 4; ++j) tile[ty + j * 8][tx] = in[(size_t)(r0 + ty + j * 8) * C + c0 + tx];
    __syncthreads();
#pragma unroll
    for (int j = 0; j < 4; ++j) out[(size_t)(c0 + ty + j * 8) * R + r0 + tx] = f2bf(tile[tx][ty + j * 8]);
}

// per (w,h): transpose [1024,64] -> [64,1024]; grid (2, 32, 48)
__global__ __launch_bounds__(256) void qkv_transpose(const float* __restrict__ Wq, const float* __restrict__ Wk,
                                                     const float* __restrict__ Wv, u16* __restrict__ out) {
    __shared__ float tile[32][33];
    const int z = blockIdx.z, w = z >> 4, h = z & 15;
    const float* in = (w == 0 ? Wq : (w == 1 ? Wk : Wv)) + (size_t)h * (DD * HD);
    u16* op = out + (size_t)(w * 1024 + h * 64) * DD;
    const int c0 = blockIdx.x * 32, r0 = blockIdx.y * 32;
    const int tx = threadIdx.x & 31, ty = threadIdx.x >> 5;
#pragma unroll
    for (int j = 0; j < 4; ++j) tile[ty + j * 8][tx] = in[(size_t)(r0 + ty + j * 8) * HD + c0 + tx];
    __syncthreads();
#pragma unroll
    for (int j = 0; j < 4; ++j) op[(size_t)(c0 + ty + j * 8) * DD + r0 + tx] = f2bf(tile[tx][ty + j * 8]);
}

__global__ __launch_bounds__(256) void pack_bias(const float* __restrict__ bq, const float* __restrict__ bk,
                                                 const float* __restrict__ bv, float* __restrict__ out) {
    int i = blockIdx.x * 256 + threadIdx.x;
    if (i < 3072) {
        const float* s = i < 1024 ? bq : (i < 2048 ? bk : bv);
        out[i] = s[i & 1023];
    }
}

// ---------------- GEMM: C[M,N] = A[M,K] * Bt[N,K]^T (bf16 in, fp32 acc) ----------------
// EPI 0: qk scatter + vt transposed store (bf16)
//     1: +bias+res -> f32   2: relu(+bias) -> bf16   3: same as 1
#define GBM 128
#define GBN 128
#define GBK 64

template <int EPI>
__global__ __launch_bounds__(256) void gemm_bt(const u16* __restrict__ A, const u16* __restrict__ Bt,
                                               const float* __restrict__ bias, const float* __restrict__ res,
                                               void* __restrict__ outp, void* __restrict__ outp2,
                                               int M, int N, int K) {
    __shared__ __align__(16) u16 sA[GBM * GBK];
    __shared__ __align__(16) u16 sB[GBN * GBK];
    const int t = threadIdx.x;
    const int lane = t & 63, wv = t >> 6;
    const int wm = (wv >> 1) * 64, wn = (wv & 1) * 64;
    const int lq = lane & 15, lk8 = (lane >> 4) * 8;
    const int m0 = blockIdx.y * GBM, n0 = blockIdx.x * GBN;

    f32x4 acc[4][4];
#pragma unroll
    for (int i = 0; i < 4; ++i)
#pragma unroll
        for (int j = 0; j < 4; ++j) acc[i][j] = (f32x4){0.f, 0.f, 0.f, 0.f};

    for (int k0 = 0; k0 < K; k0 += GBK) {
#pragma unroll
        for (int it = 0; it < 4; ++it) {
            int i = t + it * 256;
            int row = i >> 3, cc = (i & 7) * 8;
            u16x8 va = *(const u16x8*)(A + (size_t)(m0 + row) * K + k0 + cc);
            u16x8 vb = *(const u16x8*)(Bt + (size_t)(n0 + row) * K + k0 + cc);
            int by = (row * 128 + cc * 2) ^ ((row & 7) << 4);
            *(u16x8*)((char*)sA + by) = va;
            *(u16x8*)((char*)sB + by) = vb;
        }
        __syncthreads();
#pragma unroll
        for (int kk = 0; kk < 2; ++kk) {
            bf16x8 af[4], bfr[4];
#pragma unroll
            for (int mf = 0; mf < 4; ++mf) {
                int row = wm + mf * 16 + lq;
                int by = (row * 128 + kk * 64 + lk8 * 2) ^ ((row & 7) << 4);
                af[mf] = *(const bf16x8*)((const char*)sA + by);
            }
#pragma unroll
            for (int nf = 0; nf < 4; ++nf) {
                int row = wn + nf * 16 + lq;
                int by = (row * 128 + kk * 64 + lk8 * 2) ^ ((row & 7) << 4);
                bfr[nf] = *(const bf16x8*)((const char*)sB + by);
            }
#pragma unroll
            for (int mf = 0; mf < 4; ++mf)
#pragma unroll
                for (int nf = 0; nf < 4; ++nf)
                    acc[mf][nf] = __builtin_amdgcn_mfma_f32_16x16x32_bf16(af[mf], bfr[nf], acc[mf][nf], 0, 0, 0);
        }
        __syncthreads();
    }

    const int rbase = (lane >> 4) * 4;
#pragma unroll
    for (int mf = 0; mf < 4; ++mf) {
#pragma unroll
        for (int nf = 0; nf < 4; ++nf) {
            int gn = n0 + wn + nf * 16 + lq;
            float bv = bias[gn];
            if (EPI == 0) {
                int which = gn >> 10, hh = (gn >> 6) & 15, hd = gn & 63;
                int gm0 = m0 + wm + mf * 16 + rbase;
                int b = gm0 >> 11, tt2 = gm0 & 2047;
                if (which == 2) {
                    // V: store transposed, vectorized: Vt[b][h][hd][t]
                    u16x4 pk;
#pragma unroll
                    for (int r = 0; r < 4; ++r) pk[r] = f2bf(acc[mf][nf][r] + bv);
                    *(u16x4*)((u16*)outp2 + ((size_t)(b * HH + hh) * HD + hd) * TT + tt2) = pk;
                } else {
                    // Q (pre-scaled) / K: [2][B][H][T][HD]
                    float scl = (which == 0) ? QSCL : 1.f;
                    size_t off0 = (size_t)which * ((size_t)BB * HH * TT * HD) +
                                  ((size_t)(b * HH + hh) * TT + tt2) * HD + hd;
#pragma unroll
                    for (int r = 0; r < 4; ++r)
                        ((u16*)outp)[off0 + (size_t)r * HD] = f2bf((acc[mf][nf][r] + bv) * scl);
                }
            } else {
#pragma unroll
                for (int r = 0; r < 4; ++r) {
                    int gm = m0 + wm + mf * 16 + rbase + r;
                    float val = acc[mf][nf][r] + bv;
                    if (EPI == 2) {
                        ((u16*)outp)[(size_t)gm * N + gn] = f2bf(val > 0.f ? val : 0.f);
                    } else {
                        ((float*)outp)[(size_t)gm * N + gn] = val + res[(size_t)gm * N + gn];
                    }
                }
            }
        }
    }
}

// ---------------- flash attention ----------------
// qk layout: [2][B][H][T][HD] bf16 (Q pre-scaled by QSCL). vt: [B][H][HD][T] bf16.
// out ctx: [B][T][D] bf16. grid (T/64, B*H), block 256 (4 waves x 16 q-rows), KV tile = 64
__global__ __launch_bounds__(256) void attn_kernel(const u16* __restrict__ qk, const u16* __restrict__ vt,
                                                   u16* __restrict__ ctx) {
    const int t = threadIdx.x, wv = t >> 6, lane = t & 63;
    const int lq = lane & 15, lk8 = (lane >> 4) * 8;
    const int qt = blockIdx.x, bh = blockIdx.y;
    const size_t WSTR = (size_t)BB * HH * TT * HD;
    const u16* qp = qk + (size_t)bh * TT * HD;
    const u16* kp = qp + WSTR;
    const u16* vtp = vt + (size_t)bh * HD * TT;  // [64][2048]
    const int qr = qt * 64 + wv * 16;

    __shared__ __align__(16) u16 sK[64 * 64];
    __shared__ __align__(16) u16 sVt[64 * 64];
    __shared__ __align__(16) u16 sP[4][16 * 64];

    const bf16x8 qf0 = *(const bf16x8*)(qp + (size_t)(qr + lq) * HD + lk8);
    const bf16x8 qf1 = *(const bf16x8*)(qp + (size_t)(qr + lq) * HD + lk8 + 32);

    float mrun = -INFINITY, lsum = 0.f;
    f32x4 o[4];
#pragma unroll
    for (int i = 0; i < 4; ++i) o[i] = (f32x4){0.f, 0.f, 0.f, 0.f};

    for (int kt = 0; kt < TT / 64; ++kt) {
        const int kb = kt * 64;
        __syncthreads();
        // stage K tile [64 k][64 d] and Vt tile [64 d][64 t], both swizzled, vectorized
#pragma unroll
        for (int it = 0; it < 2; ++it) {
            int i = t + it * 256;
            int row = i >> 3, cc = (i & 7) * 8;
            u16x8 kvv = *(const u16x8*)(kp + (size_t)(kb + row) * HD + cc);
            u16x8 vvv = *(const u16x8*)(vtp + (size_t)row * TT + kb + cc);
            int by = (row * 128 + cc * 2) ^ ((row & 7) << 4);
            *(u16x8*)((char*)sK + by) = kvv;
            *(u16x8*)((char*)sVt + by) = vvv;
        }
        __syncthreads();

        // S^T = K * Q^T  (lane owns q = lq; rows = keys). Scores already in log2 domain.
        f32x4 s[4];
#pragma unroll
        for (int st = 0; st < 4; ++st) {
            int krow = st * 16 + lq;
            int sw = (krow & 7) << 4;
            bf16x8 kf0 = *(const bf16x8*)((const char*)sK + ((krow * 128 + lk8 * 2) ^ sw));
            bf16x8 kf1 = *(const bf16x8*)((const char*)sK + ((krow * 128 + 64 + lk8 * 2) ^ sw));
            f32x4 z = (f32x4){0.f, 0.f, 0.f, 0.f};
            z = __builtin_amdgcn_mfma_f32_16x16x32_bf16(kf0, qf0, z, 0, 0, 0);
            z = __builtin_amdgcn_mfma_f32_16x16x32_bf16(kf1, qf1, z, 0, 0, 0);
            s[st] = z;
        }
        // online softmax in exp2 domain; defer-max (T13) threshold 11 (2^11 = 2048, bf16-safe)
        float tmax = -INFINITY;
#pragma unroll
        for (int st = 0; st < 4; ++st)
#pragma unroll
            for (int r = 0; r < 4; ++r) tmax = fmaxf(tmax, s[st][r]);
        tmax = fmaxf(tmax, __shfl_xor(tmax, 16));
        tmax = fmaxf(tmax, __shfl_xor(tmax, 32));
        if (!__all((int)(tmax <= mrun + 11.0f))) {
            float mnew = fmaxf(mrun, tmax);
            float alpha = exp2f(mrun - mnew);
            lsum *= alpha;
#pragma unroll
            for (int nd = 0; nd < 4; ++nd) o[nd] *= alpha;
            mrun = mnew;
        }
        float psum = 0.f;
#pragma unroll
        for (int st = 0; st < 4; ++st)
#pragma unroll
            for (int r = 0; r < 4; ++r) {
                float p = exp2f(s[st][r] - mrun);
                s[st][r] = p;
                psum += p;
            }
        psum += __shfl_xor(psum, 16);
        psum += __shfl_xor(psum, 32);
        lsum += psum;
        // write P (bf16) to per-wave LDS: [16 q][64 k], swizzled (no block barrier needed)
#pragma unroll
        for (int st = 0; st < 4; ++st) {
            u16x4 pk;
#pragma unroll
            for (int r = 0; r < 4; ++r) pk[r] = f2bf(s[st][r]);
            int col = st * 16 + (lane >> 4) * 4;
            int by = (lq * 128 + col * 2) ^ ((lq & 7) << 4);
            *(u16x4*)((char*)sP[wv] + by) = pk;
        }
        // O^T += V^T * P^T  (lane owns q = lq in cols)
#pragma unroll
        for (int nd = 0; nd < 4; ++nd) {
            int drow = nd * 16 + lq;
            int vsw = (drow & 7) << 4;
            bf16x8 vf0 = *(const bf16x8*)((const char*)sVt + ((drow * 128 + lk8 * 2) ^ vsw));
            bf16x8 vf1 = *(const bf16x8*)((const char*)sVt + ((drow * 128 + 64 + lk8 * 2) ^ vsw));
            int psw = (lq & 7) << 4;
            bf16x8 pf0 = *(const bf16x8*)((const char*)sP[wv] + ((lq * 128 + lk8 * 2) ^ psw));
            bf16x8 pf1 = *(const bf16x8*)((const char*)sP[wv] + ((lq * 128 + 64 + lk8 * 2) ^ psw));
            o[nd] = __builtin_amdgcn_mfma_f32_16x16x32_bf16(vf0, pf0, o[nd], 0, 0, 0);
            o[nd] = __builtin_amdgcn_mfma_f32_16x16x32_bf16(vf1, pf1, o[nd], 0, 0, 0);
        }
    }

    const float inv = 1.f / lsum;
    const int b = bh >> 4, h = bh & 15;
    const size_t orow = ((size_t)b * TT + (qr + lq)) * DD + h * HD;
    const int rbase = (lane >> 4) * 4;
#pragma unroll
    for (int nd = 0; nd < 4; ++nd) {
        u16x4 ov;
#pragma unroll
        for (int r = 0; r < 4; ++r) ov[r] = f2bf(o[nd][r] * inv);
        *(u16x4*)(ctx + orow + nd * 16 + rbase) = ov;
    }
}

// ---------------- layernorm (one block per row of 1024) ----------------
template <bool WB>
__global__ __launch_bounds__(256) void ln_kernel(const float* __restrict__ y, const float* __restrict__ g,
                                                 const float* __restrict__ b, float* __restrict__ of,
                                                 u16* __restrict__ ob) {
    const int row = blockIdx.x, t = threadIdx.x;
    const float4 v = ((const float4*)(y + (size_t)row * DD))[t];
    float s = v.x + v.y + v.z + v.w;
    float q = v.x * v.x + v.y * v.y + v.z * v.z + v.w * v.w;
#pragma unroll
    for (int m = 1; m < 64; m <<= 1) {
        s += __shfl_xor(s, m);
        q += __shfl_xor(q, m);
    }
    __shared__ float red[8];
    const int wv = t >> 6, ln = t & 63;
    if (ln == 0) {
        red[wv] = s;
        red[4 + wv] = q;
    }
    __syncthreads();
    s = red[0] + red[1] + red[2] + red[3];
    q = red[4] + red[5] + red[6] + red[7];
    const float mu = s * (1.f / DD);
    const float var = q * (1.f / DD) - mu * mu;
    const float rstd = rsqrtf(var + 1e-5f);
    const float4 gg = ((const float4*)g)[t];
    const float4 bb = ((const float4*)b)[t];
    float4 o;
    o.x = (v.x - mu) * rstd * gg.x + bb.x;
    o.y = (v.y - mu) * rstd * gg.y + bb.y;
    o.z = (v.z - mu) * rstd * gg.z + bb.z;
    o.w = (v.w - mu) * rstd * gg.w + bb.w;
    ((float4*)(of + (size_t)row * DD))[t] = o;
    if (WB) {
        u16x4 u;
        u[0] = f2bf(o.x); u[1] = f2bf(o.y); u[2] = f2bf(o.z); u[3] = f2bf(o.w);
        *(u16x4*)(ob + (size_t)row * DD + t * 4) = u;
    }
}

// ---------------- launch ----------------
extern "C" void kernel_launch(void* const* d_in, const int* in_sizes, int n_in,
                              void* d_out, int out_size, void* d_ws, size_t ws_size,
                              hipStream_t stream) {
    const float* x   = (const float*)d_in[0];
    const float* Wq  = (const float*)d_in[1];
    const float* bq  = (const float*)d_in[2];
    const float* Wk  = (const float*)d_in[3];
    const float* bk  = (const float*)d_in[4];
    const float* Wv  = (const float*)d_in[5];
    const float* bv  = (const float*)d_in[6];
    const float* Wo  = (const float*)d_in[7];
    const float* bo  = (const float*)d_in[8];
    const float* g1  = (const float*)d_in[9];
    const float* be1 = (const float*)d_in[10];
    const float* W1  = (const float*)d_in[11];
    const float* b1  = (const float*)d_in[12];
    const float* W2  = (const float*)d_in[13];
    const float* b2  = (const float*)d_in[14];
    const float* g2  = (const float*)d_in[15];
    const float* be2 = (const float*)d_in[16];
    float* out = (float*)d_out;

    char* ws = (char*)d_ws;
    u16*   xb    = (u16*)(ws + 0);           // 16 MB   (reused as ctx)
    u16*   wqkvt = (u16*)(ws + 16777216);    // 6 MB
    u16*   wot   = (u16*)(ws + 23068672);    // 2 MB
    u16*   w1t   = (u16*)(ws + 25165824);    // 4 MB
    u16*   w2t   = (u16*)(ws + 29360128);    // 4 MB
    float* bqkv  = (float*)(ws + 33554432);  // 12 KB
    u16*   qkb   = (u16*)(ws + 33566720);    // 32 MB Q,K  (region reused as h: 48MB total)
    u16*   vtb   = qkb + (size_t)2 * BB * HH * TT * HD;  // 16 MB Vt
    float* y1    = (float*)(ws + 83898368);  // 32 MB  (reused as y2)
    float* x1f   = (float*)(ws + 117452800); // 32 MB
    u16*   x1b   = (u16*)(ws + 151007232);   // 16 MB
    u16*   ctx   = xb;
    u16*   hbuf  = qkb;
    float* y2    = y1;

    const int M = BB * TT;  // 8192

    // conversions
    convert_x<<<dim3((M * DD / 8 + 255) / 256), 256, 0, stream>>>(x, xb, M * DD / 8);
    qkv_transpose<<<dim3(2, 32, 48), 256, 0, stream>>>(Wq, Wk, Wv, wqkvt);
    transpose_conv<<<dim3(32, 32), 256, 0, stream>>>(Wo, wot, DD, DD);
    transpose_conv<<<dim3(64, 32), 256, 0, stream>>>(W1, w1t, DD, FF);
    transpose_conv<<<dim3(32, 64), 256, 0, stream>>>(W2, w2t, FF, DD);
    pack_bias<<<dim3(12), 256, 0, stream>>>(bq, bk, bv, bqkv);

    // QKV projection (Q pre-scaled, V stored transposed)
    gemm_bt<0><<<dim3(3 * DD / GBN, M / GBM), 256, 0, stream>>>(xb, wqkvt, bqkv, nullptr, qkb, vtb, M, 3 * DD, DD);
    // attention
    attn_kernel<<<dim3(TT / 64, BB * HH), 256, 0, stream>>>(qkb, vtb, ctx);
    // output projection + bias + residual(x)
    gemm_bt<1><<<dim3(DD / GBN, M / GBM), 256, 0, stream>>>(ctx, wot, bo, x, y1, nullptr, M, DD, DD);
    // LN1 -> x1f (f32) + x1b (bf16)
    ln_kernel<true><<<dim3(M), 256, 0, stream>>>(y1, g1, be1, x1f, x1b);
    // FFN1 (relu)
    gemm_bt<2><<<dim3(FF / GBN, M / GBM), 256, 0, stream>>>(x1b, w1t, b1, nullptr, hbuf, nullptr, M, FF, DD);
    // FFN2 + bias + residual(x1f)
    gemm_bt<3><<<dim3(DD / GBN, M / GBM), 256, 0, stream>>>(hbuf, w2t, b2, x1f, y2, nullptr, M, DD, FF);
    // LN2 -> out
    ln_kernel<false><<<dim3(M), 256, 0, stream>>>(y2, g2, be2, out, nullptr);
}

// Round 3
// 403.471 us; speedup vs baseline: 1.2955x; 1.0034x over previous
//
#include <hip/hip_runtime.h>
#include <hip/hip_bf16.h>

// ---- constants for this problem ----
#define BB 4
#define TT 2048
#define DD 1024
#define HH 16
#define HD 64
#define FF 2048
// Q pre-scale: 1/sqrt(64) * log2(e)  (softmax runs in exp2 domain)
#define QSCL 0.1803368801111204f

typedef unsigned short u16;
typedef __bf16 bf16x8 __attribute__((ext_vector_type(8)));
typedef float f32x4 __attribute__((ext_vector_type(4)));
typedef unsigned short u16x8 __attribute__((ext_vector_type(8)));
typedef unsigned short u16x4 __attribute__((ext_vector_type(4)));

// native bf16 round-to-nearest-even (v_cvt_pk_bf16_f32 on gfx950)
__device__ __forceinline__ u16 f2bf(float f) {
    return __builtin_bit_cast(u16, (__bf16)f);
}

// async global->LDS, 16B per lane; LDS dest = wave-uniform base + lane*16
__device__ __forceinline__ void gload16(const void* g, void* l) {
    __builtin_amdgcn_global_load_lds((const __attribute__((address_space(1))) void*)g,
                                     (__attribute__((address_space(3))) void*)l, 16, 0, 0);
}

// ---------------- conversion kernels ----------------
__global__ __launch_bounds__(256) void convert_x(const float* __restrict__ in, u16* __restrict__ out, int n8) {
    int i = blockIdx.x * 256 + threadIdx.x;
    if (i >= n8) return;
    const float4* p = (const float4*)in + (size_t)i * 2;
    float4 a = p[0], b = p[1];
    u16x8 o;
    o[0] = f2bf(a.x); o[1] = f2bf(a.y); o[2] = f2bf(a.z); o[3] = f2bf(a.w);
    o[4] = f2bf(b.x); o[5] = f2bf(b.y); o[6] = f2bf(b.z); o[7] = f2bf(b.w);
    ((u16x8*)out)[i] = o;
}

// out[c][r] = bf16(in[r][c]) ; grid (C/32, R/32), block 256
__global__ __launch_bounds__(256) void transpose_conv(const float* __restrict__ in, u16* __restrict__ out, int R, int C) {
    __shared__ float tile[32][33];
    const int c0 = blockIdx.x * 32, r0 = blockIdx.y * 32;
    const int tx = threadIdx.x & 31, ty = threadIdx.x >> 5;
#pragma unroll
    for (int j = 0; j < 4; ++j) tile[ty + j * 8][tx] = in[(size_t)(r0 + ty + j * 8) * C + c0 + tx];
    __syncthreads();
#pragma unroll
    for (int j = 0; j < 4; ++j) out[(size_t)(c0 + ty + j * 8) * R + r0 + tx] = f2bf(tile[tx][ty + j * 8]);
}

// per (w,h): transpose [1024,64] -> [64,1024]; grid (2, 32, 48)
__global__ __launch_bounds__(256) void qkv_transpose(const float* __restrict__ Wq, const float* __restrict__ Wk,
                                                     const float* __restrict__ Wv, u16* __restrict__ out) {
    __shared__ float tile[32][33];
    const int z = blockIdx.z, w = z >> 4, h = z & 15;
    const float* in = (w == 0 ? Wq : (w == 1 ? Wk : Wv)) + (size_t)h * (DD * HD);
    u16* op = out + (size_t)(w * 1024 + h * 64) * DD;
    const int c0 = blockIdx.x * 32, r0 = blockIdx.y * 32;
    const int tx = threadIdx.x & 31, ty = threadIdx.x >> 5;
#pragma unroll
    for (int j = 0; j < 4; ++j) tile[ty + j * 8][tx] = in[(size_t)(r0 + ty + j * 8) * HD + c0 + tx];
    __syncthreads();
#pragma unroll
    for (int j = 0; j < 4; ++j) op[(size_t)(c0 + ty + j * 8) * DD + r0 + tx] = f2bf(tile[tx][ty + j * 8]);
}

__global__ __launch_bounds__(256) void pack_bias(const float* __restrict__ bq, const float* __restrict__ bk,
                                                 const float* __restrict__ bv, float* __restrict__ out) {
    int i = blockIdx.x * 256 + threadIdx.x;
    if (i < 3072) {
        const float* s = i < 1024 ? bq : (i < 2048 ? bk : bv);
        out[i] = s[i & 1023];
    }
}

// ---------------- GEMM: C[M,N] = A[M,K] * Bt[N,K]^T (bf16 in, fp32 acc) ----------------
// m97 structure: global_load_lds(16B) staging, single LDS buffer, 2 barriers/K-step.
// LDS layout swizzled: byte(row,colb) = row*128 + (colb ^ ((row&7)<<4)); achieved with a
// linear LDS dest + inverse-swizzled global source column (rule 21).
// EPI 0: qk scatter + vt transposed store (bf16)
//     1: +bias+res -> f32   2: relu(+bias) -> bf16   3: same as 1
#define GBM 128
#define GBN 128
#define GBK 64

template <int EPI>
__global__ __launch_bounds__(256) void gemm_bt(const u16* __restrict__ A, const u16* __restrict__ Bt,
                                               const float* __restrict__ bias, const float* __restrict__ res,
                                               void* __restrict__ outp, void* __restrict__ outp2,
                                               int M, int N, int K) {
    __shared__ __align__(16) u16 sA[GBM * GBK];
    __shared__ __align__(16) u16 sB[GBN * GBK];
    const int t = threadIdx.x;
    const int lane = t & 63, wv = t >> 6;
    const int wm = (wv >> 1) * 64, wn = (wv & 1) * 64;
    const int lq = lane & 15, lk8 = (lane >> 4) * 8;
    const int m0 = blockIdx.y * GBM, n0 = blockIdx.x * GBN;

    // staging geometry: wave wv stages rows [wv*32, wv*32+32) of both sA and sB,
    // 4 issues of 1KB (8 rows) each. lane -> (lr=lane>>3 row-in-group, ch=lane&7 chunk).
    const int lr = lane >> 3, ch = lane & 7;
    const int colel = (ch ^ lr) << 3;  // inverse-swizzled source column (elements)
    const u16* Abase = A + (size_t)(m0 + wv * 32 + lr) * K + colel;
    const u16* Bbase = Bt + (size_t)(n0 + wv * 32 + lr) * K + colel;
    char* sAw = (char*)sA + wv * 32 * 128;
    char* sBw = (char*)sB + wv * 32 * 128;

    f32x4 acc[4][4];
#pragma unroll
    for (int i = 0; i < 4; ++i)
#pragma unroll
        for (int j = 0; j < 4; ++j) acc[i][j] = (f32x4){0.f, 0.f, 0.f, 0.f};

    for (int k0 = 0; k0 < K; k0 += GBK) {
#pragma unroll
        for (int i = 0; i < 4; ++i) {
            gload16(Abase + (size_t)i * 8 * K + k0, sAw + i * 1024);
            gload16(Bbase + (size_t)i * 8 * K + k0, sBw + i * 1024);
        }
        __syncthreads();
#pragma unroll
        for (int kk = 0; kk < 2; ++kk) {
            bf16x8 af[4], bfr[4];
#pragma unroll
            for (int mf = 0; mf < 4; ++mf) {
                int row = wm + mf * 16 + lq;
                int by = (row * 128 + kk * 64 + lk8 * 2) ^ ((row & 7) << 4);
                af[mf] = *(const bf16x8*)((const char*)sA + by);
            }
#pragma unroll
            for (int nf = 0; nf < 4; ++nf) {
                int row = wn + nf * 16 + lq;
                int by = (row * 128 + kk * 64 + lk8 * 2) ^ ((row & 7) << 4);
                bfr[nf] = *(const bf16x8*)((const char*)sB + by);
            }
#pragma unroll
            for (int mf = 0; mf < 4; ++mf)
#pragma unroll
                for (int nf = 0; nf < 4; ++nf)
                    acc[mf][nf] = __builtin_amdgcn_mfma_f32_16x16x32_bf16(af[mf], bfr[nf], acc[mf][nf], 0, 0, 0);
        }
        __syncthreads();
    }

    const int rbase = (lane >> 4) * 4;
#pragma unroll
    for (int mf = 0; mf < 4; ++mf) {
#pragma unroll
        for (int nf = 0; nf < 4; ++nf) {
            int gn = n0 + wn + nf * 16 + lq;
            float bv = bias[gn];
            if (EPI == 0) {
                int which = gn >> 10, hh = (gn >> 6) & 15, hd = gn & 63;
                int gm0 = m0 + wm + mf * 16 + rbase;
                int b = gm0 >> 11, tt2 = gm0 & 2047;
                if (which == 2) {
                    // V: store transposed, vectorized: Vt[b][h][hd][t]
                    u16x4 pk;
#pragma unroll
                    for (int r = 0; r < 4; ++r) pk[r] = f2bf(acc[mf][nf][r] + bv);
                    *(u16x4*)((u16*)outp2 + ((size_t)(b * HH + hh) * HD + hd) * TT + tt2) = pk;
                } else {
                    // Q (pre-scaled) / K: [2][B][H][T][HD]
                    float scl = (which == 0) ? QSCL : 1.f;
                    size_t off0 = (size_t)which * ((size_t)BB * HH * TT * HD) +
                                  ((size_t)(b * HH + hh) * TT + tt2) * HD + hd;
#pragma unroll
                    for (int r = 0; r < 4; ++r)
                        ((u16*)outp)[off0 + (size_t)r * HD] = f2bf((acc[mf][nf][r] + bv) * scl);
                }
            } else {
#pragma unroll
                for (int r = 0; r < 4; ++r) {
                    int gm = m0 + wm + mf * 16 + rbase + r;
                    float val = acc[mf][nf][r] + bv;
                    if (EPI == 2) {
                        ((u16*)outp)[(size_t)gm * N + gn] = f2bf(val > 0.f ? val : 0.f);
                    } else {
                        ((float*)outp)[(size_t)gm * N + gn] = val + res[(size_t)gm * N + gn];
                    }
                }
            }
        }
    }
}

// ---------------- flash attention ----------------
// qk layout: [2][B][H][T][HD] bf16 (Q pre-scaled by QSCL). vt: [B][H][HD][T] bf16.
// out ctx: [B][T][D] bf16. grid (T/64, B*H), block 256 (4 waves x 16 q-rows), KV tile = 64.
// Double-buffered K/V staging via global_load_lds + counted vmcnt(4): next tile's loads
// stay in flight across both barriers and the whole compute phase (T3/T4-lite).
__global__ __launch_bounds__(256) void attn_kernel(const u16* __restrict__ qk, const u16* __restrict__ vt,
                                                   u16* __restrict__ ctx) {
    const int t = threadIdx.x, wv = t >> 6, lane = t & 63;
    const int lq = lane & 15, lk8 = (lane >> 4) * 8;
    const int lr = lane >> 3, ch = lane & 7;
    const int colel = (ch ^ lr) << 3;
    const int qt = blockIdx.x, bh = blockIdx.y;
    const size_t WSTR = (size_t)BB * HH * TT * HD;
    const u16* qp = qk + (size_t)bh * TT * HD;
    const u16* kp = qp + WSTR;
    const u16* vtp = vt + (size_t)bh * HD * TT;  // [64][2048]
    const int qr = qt * 64 + wv * 16;

    __shared__ __align__(16) u16 sK[2][64 * 64];
    __shared__ __align__(16) u16 sVt[2][64 * 64];
    __shared__ __align__(16) u16 sP[4][16 * 64];

    // staging bases: wave wv stages rows [wv*16, wv*16+16) of sK and sVt (2 issues each)
    const u16* kbase = kp + (size_t)(wv * 16 + lr) * HD + colel;
    const u16* vbase = vtp + (size_t)(wv * 16 + lr) * TT + colel;
    char* dK = (char*)sK + wv * 16 * 128;
    char* dV = (char*)sVt + wv * 16 * 128;

#define ATTN_STAGE(bufi, kb)                                                        \
    do {                                                                            \
        _Pragma("unroll") for (int ii = 0; ii < 2; ++ii) {                          \
            gload16(kbase + (size_t)((kb) + ii * 8) * HD, dK + (bufi) * 8192 + ii * 1024); \
            gload16(vbase + (size_t)(ii * 8) * TT + (kb), dV + (bufi) * 8192 + ii * 1024); \
        }                                                                           \
    } while (0)

    const bf16x8 qf0 = *(const bf16x8*)(qp + (size_t)(qr + lq) * HD + lk8);
    const bf16x8 qf1 = *(const bf16x8*)(qp + (size_t)(qr + lq) * HD + lk8 + 32);

    float mrun = -INFINITY, lsum = 0.f;
    f32x4 o[4];
#pragma unroll
    for (int i = 0; i < 4; ++i) o[i] = (f32x4){0.f, 0.f, 0.f, 0.f};

    ATTN_STAGE(0, 0);

    const int NT = TT / 64;
    for (int kt = 0; kt < NT; ++kt) {
        const int cur = kt & 1;
        if (kt + 1 < NT) {
            ATTN_STAGE(cur ^ 1, (kt + 1) * 64);
            asm volatile("s_waitcnt vmcnt(4)" ::: "memory");  // tile kt's 4 loads landed
        } else {
            asm volatile("s_waitcnt vmcnt(0)" ::: "memory");
        }
        __builtin_amdgcn_s_barrier();
        __builtin_amdgcn_sched_barrier(0);

        const char* sKc = (const char*)sK + cur * 8192;
        const char* sVc = (const char*)sVt + cur * 8192;

        // S^T = K * Q^T  (lane owns q = lq; rows = keys). Scores already in log2 domain.
        f32x4 s[4];
#pragma unroll
        for (int st = 0; st < 4; ++st) {
            int krow = st * 16 + lq;
            int sw = (krow & 7) << 4;
            bf16x8 kf0 = *(const bf16x8*)(sKc + ((krow * 128 + lk8 * 2) ^ sw));
            bf16x8 kf1 = *(const bf16x8*)(sKc + ((krow * 128 + 64 + lk8 * 2) ^ sw));
            f32x4 z = (f32x4){0.f, 0.f, 0.f, 0.f};
            z = __builtin_amdgcn_mfma_f32_16x16x32_bf16(kf0, qf0, z, 0, 0, 0);
            z = __builtin_amdgcn_mfma_f32_16x16x32_bf16(kf1, qf1, z, 0, 0, 0);
            s[st] = z;
        }
        // online softmax in exp2 domain; defer-max (T13) threshold 11
        float t0 = fmaxf(fmaxf(s[0][0], s[0][1]), fmaxf(s[0][2], s[0][3]));
        float t1 = fmaxf(fmaxf(s[1][0], s[1][1]), fmaxf(s[1][2], s[1][3]));
        float t2 = fmaxf(fmaxf(s[2][0], s[2][1]), fmaxf(s[2][2], s[2][3]));
        float t3 = fmaxf(fmaxf(s[3][0], s[3][1]), fmaxf(s[3][2], s[3][3]));
        float tmax = fmaxf(fmaxf(t0, t1), fmaxf(t2, t3));
        tmax = fmaxf(tmax, __shfl_xor(tmax, 16));
        tmax = fmaxf(tmax, __shfl_xor(tmax, 32));
        if (!__all((int)(tmax <= mrun + 11.0f))) {
            float mnew = fmaxf(mrun, tmax);
            float alpha = exp2f(mrun - mnew);
            lsum *= alpha;
#pragma unroll
            for (int nd = 0; nd < 4; ++nd) o[nd] *= alpha;
            mrun = mnew;
        }
        f32x4 ps4 = (f32x4){0.f, 0.f, 0.f, 0.f};
#pragma unroll
        for (int st = 0; st < 4; ++st) {
#pragma unroll
            for (int r = 0; r < 4; ++r) {
                float p = exp2f(s[st][r] - mrun);
                s[st][r] = p;
            }
            ps4 += s[st];
        }
        float psum = (ps4[0] + ps4[1]) + (ps4[2] + ps4[3]);
        psum += __shfl_xor(psum, 16);
        psum += __shfl_xor(psum, 32);
        lsum += psum;
        // write P (bf16) to per-wave LDS: [16 q][64 k], swizzled (wave-private, no barrier)
#pragma unroll
        for (int st = 0; st < 4; ++st) {
            u16x4 pk;
#pragma unroll
            for (int r = 0; r < 4; ++r) pk[r] = f2bf(s[st][r]);
            int col = st * 16 + (lane >> 4) * 4;
            int by = (lq * 128 + col * 2) ^ ((lq & 7) << 4);
            *(u16x4*)((char*)sP[wv] + by) = pk;
        }
        // O^T += V^T * P^T  (lane owns q = lq in cols)
#pragma unroll
        for (int nd = 0; nd < 4; ++nd) {
            int drow = nd * 16 + lq;
            int vsw = (drow & 7) << 4;
            bf16x8 vf0 = *(const bf16x8*)(sVc + ((drow * 128 + lk8 * 2) ^ vsw));
            bf16x8 vf1 = *(const bf16x8*)(sVc + ((drow * 128 + 64 + lk8 * 2) ^ vsw));
            int psw = (lq & 7) << 4;
            bf16x8 pf0 = *(const bf16x8*)((const char*)sP[wv] + ((lq * 128 + lk8 * 2) ^ psw));
            bf16x8 pf1 = *(const bf16x8*)((const char*)sP[wv] + ((lq * 128 + 64 + lk8 * 2) ^ psw));
            o[nd] = __builtin_amdgcn_mfma_f32_16x16x32_bf16(vf0, pf0, o[nd], 0, 0, 0);
            o[nd] = __builtin_amdgcn_mfma_f32_16x16x32_bf16(vf1, pf1, o[nd], 0, 0, 0);
        }
        __builtin_amdgcn_sched_barrier(0);
        __builtin_amdgcn_s_barrier();
    }

    const float inv = 1.f / lsum;
    const int b = bh >> 4, h = bh & 15;
    const size_t orow = ((size_t)b * TT + (qr + lq)) * DD + h * HD;
    const int rbase = (lane >> 4) * 4;
#pragma unroll
    for (int nd = 0; nd < 4; ++nd) {
        u16x4 ov;
#pragma unroll
        for (int r = 0; r < 4; ++r) ov[r] = f2bf(o[nd][r] * inv);
        *(u16x4*)(ctx + orow + nd * 16 + rbase) = ov;
    }
#undef ATTN_STAGE
}

// ---------------- layernorm (one block per row of 1024) ----------------
template <bool WB>
__global__ __launch_bounds__(256) void ln_kernel(const float* __restrict__ y, const float* __restrict__ g,
                                                 const float* __restrict__ b, float* __restrict__ of,
                                                 u16* __restrict__ ob) {
    const int row = blockIdx.x, t = threadIdx.x;
    const float4 v = ((const float4*)(y + (size_t)row * DD))[t];
    float s = v.x + v.y + v.z + v.w;
    float q = v.x * v.x + v.y * v.y + v.z * v.z + v.w * v.w;
#pragma unroll
    for (int m = 1; m < 64; m <<= 1) {
        s += __shfl_xor(s, m);
        q += __shfl_xor(q, m);
    }
    __shared__ float red[8];
    const int wv = t >> 6, ln = t & 63;
    if (ln == 0) {
        red[wv] = s;
        red[4 + wv] = q;
    }
    __syncthreads();
    s = red[0] + red[1] + red[2] + red[3];
    q = red[4] + red[5] + red[6] + red[7];
    const float mu = s * (1.f / DD);
    const float var = q * (1.f / DD) - mu * mu;
    const float rstd = rsqrtf(var + 1e-5f);
    const float4 gg = ((const float4*)g)[t];
    const float4 bb = ((const float4*)b)[t];
    float4 o;
    o.x = (v.x - mu) * rstd * gg.x + bb.x;
    o.y = (v.y - mu) * rstd * gg.y + bb.y;
    o.z = (v.z - mu) * rstd * gg.z + bb.z;
    o.w = (v.w - mu) * rstd * gg.w + bb.w;
    ((float4*)(of + (size_t)row * DD))[t] = o;
    if (WB) {
        u16x4 u;
        u[0] = f2bf(o.x); u[1] = f2bf(o.y); u[2] = f2bf(o.z); u[3] = f2bf(o.w);
        *(u16x4*)(ob + (size_t)row * DD + t * 4) = u;
    }
}

// ---------------- launch ----------------
extern "C" void kernel_launch(void* const* d_in, const int* in_sizes, int n_in,
                              void* d_out, int out_size, void* d_ws, size_t ws_size,
                              hipStream_t stream) {
    const float* x   = (const float*)d_in[0];
    const float* Wq  = (const float*)d_in[1];
    const float* bq  = (const float*)d_in[2];
    const float* Wk  = (const float*)d_in[3];
    const float* bk  = (const float*)d_in[4];
    const float* Wv  = (const float*)d_in[5];
    const float* bv  = (const float*)d_in[6];
    const float* Wo  = (const float*)d_in[7];
    const float* bo  = (const float*)d_in[8];
    const float* g1  = (const float*)d_in[9];
    const float* be1 = (const float*)d_in[10];
    const float* W1  = (const float*)d_in[11];
    const float* b1  = (const float*)d_in[12];
    const float* W2  = (const float*)d_in[13];
    const float* b2  = (const float*)d_in[14];
    const float* g2  = (const float*)d_in[15];
    const float* be2 = (const float*)d_in[16];
    float* out = (float*)d_out;

    char* ws = (char*)d_ws;
    u16*   xb    = (u16*)(ws + 0);           // 16 MB   (reused as ctx)
    u16*   wqkvt = (u16*)(ws + 16777216);    // 6 MB
    u16*   wot   = (u16*)(ws + 23068672);    // 2 MB
    u16*   w1t   = (u16*)(ws + 25165824);    // 4 MB
    u16*   w2t   = (u16*)(ws + 29360128);    // 4 MB
    float* bqkv  = (float*)(ws + 33554432);  // 12 KB
    u16*   qkb   = (u16*)(ws + 33566720);    // 32 MB Q,K  (region reused as h: 48MB total)
    u16*   vtb   = qkb + (size_t)2 * BB * HH * TT * HD;  // 16 MB Vt
    float* y1    = (float*)(ws + 83898368);  // 32 MB  (reused as y2)
    float* x1f   = (float*)(ws + 117452800); // 32 MB
    u16*   x1b   = (u16*)(ws + 151007232);   // 16 MB
    u16*   ctx   = xb;
    u16*   hbuf  = qkb;
    float* y2    = y1;

    const int M = BB * TT;  // 8192

    // conversions
    convert_x<<<dim3((M * DD / 8 + 255) / 256), 256, 0, stream>>>(x, xb, M * DD / 8);
    qkv_transpose<<<dim3(2, 32, 48), 256, 0, stream>>>(Wq, Wk, Wv, wqkvt);
    transpose_conv<<<dim3(32, 32), 256, 0, stream>>>(Wo, wot, DD, DD);
    transpose_conv<<<dim3(64, 32), 256, 0, stream>>>(W1, w1t, DD, FF);
    transpose_conv<<<dim3(32, 64), 256, 0, stream>>>(W2, w2t, FF, DD);
    pack_bias<<<dim3(12), 256, 0, stream>>>(bq, bk, bv, bqkv);

    // QKV projection (Q pre-scaled, V stored transposed)
    gemm_bt<0><<<dim3(3 * DD / GBN, M / GBM), 256, 0, stream>>>(xb, wqkvt, bqkv, nullptr, qkb, vtb, M, 3 * DD, DD);
    // attention
    attn_kernel<<<dim3(TT / 64, BB * HH), 256, 0, stream>>>(qkb, vtb, ctx);
    // output projection + bias + residual(x)
    gemm_bt<1><<<dim3(DD / GBN, M / GBM), 256, 0, stream>>>(ctx, wot, bo, x, y1, nullptr, M, DD, DD);
    // LN1 -> x1f (f32) + x1b (bf16)
    ln_kernel<true><<<dim3(M), 256, 0, stream>>>(y1, g1, be1, x1f, x1b);
    // FFN1 (relu)
    gemm_bt<2><<<dim3(FF / GBN, M / GBM), 256, 0, stream>>>(x1b, w1t, b1, nullptr, hbuf, nullptr, M, FF, DD);
    // FFN2 + bias + residual(x1f)
    gemm_bt<3><<<dim3(DD / GBN, M / GBM), 256, 0, stream>>>(hbuf, w2t, b2, x1f, y2, nullptr, M, DD, FF);
    // LN2 -> out
    ln_kernel<false><<<dim3(M), 256, 0, stream>>>(y2, g2, be2, out, nullptr);
}

// Round 4
// 394.502 us; speedup vs baseline: 1.3250x; 1.0227x over previous
//
#include <hip/hip_runtime.h>
#include <hip/hip_bf16.h>

// ---- constants for this problem ----
#define BB 4
#define TT 2048
#define DD 1024
#define HH 16
#define HD 64
#define FF 2048
// Q pre-scale: 1/sqrt(64) * log2(e)  (softmax runs in exp2 domain)
#define QSCL 0.1803368801111204f

typedef unsigned short u16;
typedef __bf16 bf16x8 __attribute__((ext_vector_type(8)));
typedef float f32x4 __attribute__((ext_vector_type(4)));
typedef unsigned short u16x8 __attribute__((ext_vector_type(8)));
typedef unsigned short u16x4 __attribute__((ext_vector_type(4)));

// native bf16 round-to-nearest-even (v_cvt_pk_bf16_f32 on gfx950)
__device__ __forceinline__ u16 f2bf(float f) {
    return __builtin_bit_cast(u16, (__bf16)f);
}

// async global->LDS, 16B per lane; LDS dest = wave-uniform base + lane*16
__device__ __forceinline__ void gload16(const void* g, void* l) {
    __builtin_amdgcn_global_load_lds((const __attribute__((address_space(1))) void*)g,
                                     (__attribute__((address_space(3))) void*)l, 16, 0, 0);
}

// ---------------- conversion kernels ----------------
__global__ __launch_bounds__(256) void convert_x(const float* __restrict__ in, u16* __restrict__ out, int n8) {
    int i = blockIdx.x * 256 + threadIdx.x;
    if (i >= n8) return;
    const float4* p = (const float4*)in + (size_t)i * 2;
    float4 a = p[0], b = p[1];
    u16x8 o;
    o[0] = f2bf(a.x); o[1] = f2bf(a.y); o[2] = f2bf(a.z); o[3] = f2bf(a.w);
    o[4] = f2bf(b.x); o[5] = f2bf(b.y); o[6] = f2bf(b.z); o[7] = f2bf(b.w);
    ((u16x8*)out)[i] = o;
}

// out[c][r] = bf16(in[r][c]) ; grid (C/32, R/32), block 256
__global__ __launch_bounds__(256) void transpose_conv(const float* __restrict__ in, u16* __restrict__ out, int R, int C) {
    __shared__ float tile[32][33];
    const int c0 = blockIdx.x * 32, r0 = blockIdx.y * 32;
    const int tx = threadIdx.x & 31, ty = threadIdx.x >> 5;
#pragma unroll
    for (int j = 0; j < 4; ++j) tile[ty + j * 8][tx] = in[(size_t)(r0 + ty + j * 8) * C + c0 + tx];
    __syncthreads();
#pragma unroll
    for (int j = 0; j < 4; ++j) out[(size_t)(c0 + ty + j * 8) * R + r0 + tx] = f2bf(tile[tx][ty + j * 8]);
}

// per (w,h): transpose [1024,64] -> [64,1024]; grid (2, 32, 48)
__global__ __launch_bounds__(256) void qkv_transpose(const float* __restrict__ Wq, const float* __restrict__ Wk,
                                                     const float* __restrict__ Wv, u16* __restrict__ out) {
    __shared__ float tile[32][33];
    const int z = blockIdx.z, w = z >> 4, h = z & 15;
    const float* in = (w == 0 ? Wq : (w == 1 ? Wk : Wv)) + (size_t)h * (DD * HD);
    u16* op = out + (size_t)(w * 1024 + h * 64) * DD;
    const int c0 = blockIdx.x * 32, r0 = blockIdx.y * 32;
    const int tx = threadIdx.x & 31, ty = threadIdx.x >> 5;
#pragma unroll
    for (int j = 0; j < 4; ++j) tile[ty + j * 8][tx] = in[(size_t)(r0 + ty + j * 8) * HD + c0 + tx];
    __syncthreads();
#pragma unroll
    for (int j = 0; j < 4; ++j) op[(size_t)(c0 + ty + j * 8) * DD + r0 + tx] = f2bf(tile[tx][ty + j * 8]);
}

__global__ __launch_bounds__(256) void pack_bias(const float* __restrict__ bq, const float* __restrict__ bk,
                                                 const float* __restrict__ bv, float* __restrict__ out) {
    int i = blockIdx.x * 256 + threadIdx.x;
    if (i < 3072) {
        const float* s = i < 1024 ? bq : (i < 2048 ? bk : bv);
        out[i] = s[i & 1023];
    }
}

// ---------------- GEMM: C[M,N] = A[M,K] * Bt[N,K]^T (bf16 in, fp32 acc) ----------------
// m97 structure: global_load_lds(16B) staging, single LDS buffer, 2 barriers/K-step.
// LDS layout swizzled: byte(row,colb) = row*128 + (colb ^ ((row&7)<<4)); achieved with a
// linear LDS dest + inverse-swizzled global source column (rule 21).
// EPI 0: qk scatter + vt transposed store (bf16)
//     1: +bias+res -> f32   2: relu(+bias) -> bf16   3: same as 1
#define GBM 128
#define GBN 128
#define GBK 64

template <int EPI>
__global__ __launch_bounds__(256) void gemm_bt(const u16* __restrict__ A, const u16* __restrict__ Bt,
                                               const float* __restrict__ bias, const float* __restrict__ res,
                                               void* __restrict__ outp, void* __restrict__ outp2,
                                               int M, int N, int K) {
    __shared__ __align__(16) u16 sA[GBM * GBK];
    __shared__ __align__(16) u16 sB[GBN * GBK];
    const int t = threadIdx.x;
    const int lane = t & 63, wv = t >> 6;
    const int wm = (wv >> 1) * 64, wn = (wv & 1) * 64;
    const int lq = lane & 15, lk8 = (lane >> 4) * 8;
    const int m0 = blockIdx.y * GBM, n0 = blockIdx.x * GBN;

    const int lr = lane >> 3, ch = lane & 7;
    const int colel = (ch ^ lr) << 3;  // inverse-swizzled source column (elements)
    const u16* Abase = A + (size_t)(m0 + wv * 32 + lr) * K + colel;
    const u16* Bbase = Bt + (size_t)(n0 + wv * 32 + lr) * K + colel;
    char* sAw = (char*)sA + wv * 32 * 128;
    char* sBw = (char*)sB + wv * 32 * 128;

    f32x4 acc[4][4];
#pragma unroll
    for (int i = 0; i < 4; ++i)
#pragma unroll
        for (int j = 0; j < 4; ++j) acc[i][j] = (f32x4){0.f, 0.f, 0.f, 0.f};

    for (int k0 = 0; k0 < K; k0 += GBK) {
#pragma unroll
        for (int i = 0; i < 4; ++i) {
            gload16(Abase + (size_t)i * 8 * K + k0, sAw + i * 1024);
            gload16(Bbase + (size_t)i * 8 * K + k0, sBw + i * 1024);
        }
        __syncthreads();
#pragma unroll
        for (int kk = 0; kk < 2; ++kk) {
            bf16x8 af[4], bfr[4];
#pragma unroll
            for (int mf = 0; mf < 4; ++mf) {
                int row = wm + mf * 16 + lq;
                int by = (row * 128 + kk * 64 + lk8 * 2) ^ ((row & 7) << 4);
                af[mf] = *(const bf16x8*)((const char*)sA + by);
            }
#pragma unroll
            for (int nf = 0; nf < 4; ++nf) {
                int row = wn + nf * 16 + lq;
                int by = (row * 128 + kk * 64 + lk8 * 2) ^ ((row & 7) << 4);
                bfr[nf] = *(const bf16x8*)((const char*)sB + by);
            }
#pragma unroll
            for (int mf = 0; mf < 4; ++mf)
#pragma unroll
                for (int nf = 0; nf < 4; ++nf)
                    acc[mf][nf] = __builtin_amdgcn_mfma_f32_16x16x32_bf16(af[mf], bfr[nf], acc[mf][nf], 0, 0, 0);
        }
        __syncthreads();
    }

    const int rbase = (lane >> 4) * 4;
#pragma unroll
    for (int mf = 0; mf < 4; ++mf) {
#pragma unroll
        for (int nf = 0; nf < 4; ++nf) {
            int gn = n0 + wn + nf * 16 + lq;
            float bv = bias[gn];
            if (EPI == 0) {
                int which = gn >> 10, hh = (gn >> 6) & 15, hd = gn & 63;
                int gm0 = m0 + wm + mf * 16 + rbase;
                int b = gm0 >> 11, tt2 = gm0 & 2047;
                if (which == 2) {
                    // V: store transposed, vectorized: Vt[b][h][hd][t]
                    u16x4 pk;
#pragma unroll
                    for (int r = 0; r < 4; ++r) pk[r] = f2bf(acc[mf][nf][r] + bv);
                    *(u16x4*)((u16*)outp2 + ((size_t)(b * HH + hh) * HD + hd) * TT + tt2) = pk;
                } else {
                    // Q (pre-scaled) / K: [2][B][H][T][HD]
                    float scl = (which == 0) ? QSCL : 1.f;
                    size_t off0 = (size_t)which * ((size_t)BB * HH * TT * HD) +
                                  ((size_t)(b * HH + hh) * TT + tt2) * HD + hd;
#pragma unroll
                    for (int r = 0; r < 4; ++r)
                        ((u16*)outp)[off0 + (size_t)r * HD] = f2bf((acc[mf][nf][r] + bv) * scl);
                }
            } else {
#pragma unroll
                for (int r = 0; r < 4; ++r) {
                    int gm = m0 + wm + mf * 16 + rbase + r;
                    float val = acc[mf][nf][r] + bv;
                    if (EPI == 2) {
                        ((u16*)outp)[(size_t)gm * N + gn] = f2bf(val > 0.f ? val : 0.f);
                    } else {
                        ((float*)outp)[(size_t)gm * N + gn] = val + res[(size_t)gm * N + gn];
                    }
                }
            }
        }
    }
}

// ---------------- flash attention ----------------
// qk layout: [2][B][H][T][HD] bf16 (Q pre-scaled by QSCL). vt: [B][H][HD][T] bf16.
// out ctx: [B][T][D] bf16.
// grid (T/128, B*H), block 256: 4 waves x 32 q-rows each (2 q-halves of 16), KV tile = 64.
// Per-score VALU amortized 2x vs 16q/wave; psum computed by chained ones-MFMA (no adds/shfl).
__global__ __launch_bounds__(256) void attn_kernel(const u16* __restrict__ qk, const u16* __restrict__ vt,
                                                   u16* __restrict__ ctx) {
    const int t = threadIdx.x, wv = t >> 6, lane = t & 63;
    const int lq = lane & 15, lk8 = (lane >> 4) * 8;
    const int lr = lane >> 3, ch = lane & 7;
    const int colel = (ch ^ lr) << 3;
    const int qt = blockIdx.x, bh = blockIdx.y;
    const size_t WSTR = (size_t)BB * HH * TT * HD;
    const u16* qp = qk + (size_t)bh * TT * HD;
    const u16* kp = qp + WSTR;
    const u16* vtp = vt + (size_t)bh * HD * TT;  // [64][2048]
    const int qr = qt * 128 + wv * 32;

    __shared__ __align__(16) u16 sK[2][64 * 64];
    __shared__ __align__(16) u16 sVt[2][64 * 64];
    __shared__ __align__(16) u16 sP[4][32 * 64];

    // staging: wave wv stages rows [wv*16, wv*16+16) of sK and sVt (2 gloads each)
    const u16* kbase = kp + (size_t)(wv * 16 + lr) * HD + colel;
    const u16* vbase = vtp + (size_t)(wv * 16 + lr) * TT + colel;
    char* dK = (char*)sK + wv * 16 * 128;
    char* dV = (char*)sVt + wv * 16 * 128;

#define ATTN_STAGE(bufi, kb)                                                        \
    do {                                                                            \
        _Pragma("unroll") for (int ii = 0; ii < 2; ++ii) {                          \
            gload16(kbase + (size_t)((kb) + ii * 8) * HD, dK + (bufi) * 8192 + ii * 1024); \
            gload16(vbase + (size_t)(ii * 8) * TT + (kb), dV + (bufi) * 8192 + ii * 1024); \
        }                                                                           \
    } while (0)

    // Q fragments: 2 q-halves x 2 d-chunks
    bf16x8 qf[2][2];
#pragma unroll
    for (int qh = 0; qh < 2; ++qh)
#pragma unroll
        for (int c = 0; c < 2; ++c)
            qf[qh][c] = *(const bf16x8*)(qp + (size_t)(qr + qh * 16 + lq) * HD + c * 32 + lk8);

    bf16x8 ones;
#pragma unroll
    for (int i = 0; i < 8; ++i) ones[i] = (__bf16)1.0f;

    float mrun[2] = {-INFINITY, -INFINITY}, lsum[2] = {0.f, 0.f};
    f32x4 o[4][2];
#pragma unroll
    for (int i = 0; i < 4; ++i)
#pragma unroll
        for (int qh = 0; qh < 2; ++qh) o[i][qh] = (f32x4){0.f, 0.f, 0.f, 0.f};

    ATTN_STAGE(0, 0);

    const int NT = TT / 64;
    for (int kt = 0; kt < NT; ++kt) {
        const int cur = kt & 1;
        if (kt + 1 < NT) {
            ATTN_STAGE(cur ^ 1, (kt + 1) * 64);
            asm volatile("s_waitcnt vmcnt(4)" ::: "memory");  // tile kt's 4 loads landed
        } else {
            asm volatile("s_waitcnt vmcnt(0)" ::: "memory");
        }
        __builtin_amdgcn_s_barrier();
        __builtin_amdgcn_sched_barrier(0);

        const char* sKc = (const char*)sK + cur * 8192;
        const char* sVc = (const char*)sVt + cur * 8192;

        // S^T = K * Q^T  (lane owns q-cols {lq, 16+lq}; rows = keys). Log2 domain.
        f32x4 s[4][2];
#pragma unroll
        for (int st = 0; st < 4; ++st) {
            int krow = st * 16 + lq;
            int sw = (krow & 7) << 4;
            bf16x8 kf0 = *(const bf16x8*)(sKc + ((krow * 128 + lk8 * 2) ^ sw));
            bf16x8 kf1 = *(const bf16x8*)(sKc + ((krow * 128 + 64 + lk8 * 2) ^ sw));
#pragma unroll
            for (int qh = 0; qh < 2; ++qh) {
                f32x4 z = (f32x4){0.f, 0.f, 0.f, 0.f};
                z = __builtin_amdgcn_mfma_f32_16x16x32_bf16(kf0, qf[qh][0], z, 0, 0, 0);
                z = __builtin_amdgcn_mfma_f32_16x16x32_bf16(kf1, qf[qh][1], z, 0, 0, 0);
                s[st][qh] = z;
            }
        }
        // tile max per q-half (reduce 16 in-lane + 2 shfl over the 4 k-row-groups)
        float tmax[2];
#pragma unroll
        for (int qh = 0; qh < 2; ++qh) {
            float a = fmaxf(fmaxf(s[0][qh][0], s[0][qh][1]), fmaxf(s[0][qh][2], s[0][qh][3]));
            float b = fmaxf(fmaxf(s[1][qh][0], s[1][qh][1]), fmaxf(s[1][qh][2], s[1][qh][3]));
            float c = fmaxf(fmaxf(s[2][qh][0], s[2][qh][1]), fmaxf(s[2][qh][2], s[2][qh][3]));
            float d = fmaxf(fmaxf(s[3][qh][0], s[3][qh][1]), fmaxf(s[3][qh][2], s[3][qh][3]));
            float m = fmaxf(fmaxf(a, b), fmaxf(c, d));
            m = fmaxf(m, __shfl_xor(m, 16));
            m = fmaxf(m, __shfl_xor(m, 32));
            tmax[qh] = m;
        }
        // defer-max (T13): rescale only when some q grew by >2^11
        if (__any((int)((tmax[0] > mrun[0] + 11.0f) | (tmax[1] > mrun[1] + 11.0f)))) {
#pragma unroll
            for (int qh = 0; qh < 2; ++qh) {
                float mnew = fmaxf(mrun[qh], tmax[qh]);
                float alpha = exp2f(mrun[qh] - mnew);
                lsum[qh] *= alpha;
#pragma unroll
                for (int nd = 0; nd < 4; ++nd) o[nd][qh] *= alpha;
                mrun[qh] = mnew;
            }
        }
#pragma unroll
        for (int st = 0; st < 4; ++st)
#pragma unroll
            for (int qh = 0; qh < 2; ++qh)
#pragma unroll
                for (int r = 0; r < 4; ++r) s[st][qh][r] = exp2f(s[st][qh][r] - mrun[qh]);
        // write P (bf16) to per-wave LDS: [32 q][64 k], swizzled (wave-private, no barrier)
#pragma unroll
        for (int st = 0; st < 4; ++st)
#pragma unroll
            for (int qh = 0; qh < 2; ++qh) {
                u16x4 pk;
#pragma unroll
                for (int r = 0; r < 4; ++r) pk[r] = f2bf(s[st][qh][r]);
                int qrow = qh * 16 + lq;
                int col = st * 16 + (lane >> 4) * 4;
                int by = (qrow * 128 + col * 2) ^ ((qrow & 7) << 4);
                *(u16x4*)((char*)sP[wv] + by) = pk;
            }
        // P fragments (B-operand) for psum + PV
        bf16x8 pf[2][2];
#pragma unroll
        for (int qh = 0; qh < 2; ++qh)
#pragma unroll
            for (int c = 0; c < 2; ++c) {
                int qrow = qh * 16 + lq;
                int by = (qrow * 128 + c * 64 + lk8 * 2) ^ ((qrow & 7) << 4);
                pf[qh][c] = *(const bf16x8*)((const char*)sP[wv] + by);
            }
        // psum via chained ones-MFMA: every lane gets its q's sum in z[0] (no shuffles)
#pragma unroll
        for (int qh = 0; qh < 2; ++qh) {
            f32x4 z = (f32x4){0.f, 0.f, 0.f, 0.f};
            z = __builtin_amdgcn_mfma_f32_16x16x32_bf16(ones, pf[qh][0], z, 0, 0, 0);
            z = __builtin_amdgcn_mfma_f32_16x16x32_bf16(ones, pf[qh][1], z, 0, 0, 0);
            lsum[qh] += z[0];
        }
        // O^T += V^T * P^T
#pragma unroll
        for (int nd = 0; nd < 4; ++nd) {
            int drow = nd * 16 + lq;
            int vsw = (drow & 7) << 4;
            bf16x8 vf0 = *(const bf16x8*)(sVc + ((drow * 128 + lk8 * 2) ^ vsw));
            bf16x8 vf1 = *(const bf16x8*)(sVc + ((drow * 128 + 64 + lk8 * 2) ^ vsw));
#pragma unroll
            for (int qh = 0; qh < 2; ++qh) {
                o[nd][qh] = __builtin_amdgcn_mfma_f32_16x16x32_bf16(vf0, pf[qh][0], o[nd][qh], 0, 0, 0);
                o[nd][qh] = __builtin_amdgcn_mfma_f32_16x16x32_bf16(vf1, pf[qh][1], o[nd][qh], 0, 0, 0);
            }
        }
        __builtin_amdgcn_sched_barrier(0);
        __builtin_amdgcn_s_barrier();
    }

    const int b = bh >> 4, h = bh & 15;
    const int rbase = (lane >> 4) * 4;
#pragma unroll
    for (int qh = 0; qh < 2; ++qh) {
        const float inv = 1.f / lsum[qh];
        const size_t orow = ((size_t)b * TT + (qr + qh * 16 + lq)) * DD + h * HD;
#pragma unroll
        for (int nd = 0; nd < 4; ++nd) {
            u16x4 ov;
#pragma unroll
            for (int r = 0; r < 4; ++r) ov[r] = f2bf(o[nd][qh][r] * inv);
            *(u16x4*)(ctx + orow + nd * 16 + rbase) = ov;
        }
    }
#undef ATTN_STAGE
}

// ---------------- layernorm (one block per row of 1024) ----------------
template <bool WB>
__global__ __launch_bounds__(256) void ln_kernel(const float* __restrict__ y, const float* __restrict__ g,
                                                 const float* __restrict__ b, float* __restrict__ of,
                                                 u16* __restrict__ ob) {
    const int row = blockIdx.x, t = threadIdx.x;
    const float4 v = ((const float4*)(y + (size_t)row * DD))[t];
    float s = v.x + v.y + v.z + v.w;
    float q = v.x * v.x + v.y * v.y + v.z * v.z + v.w * v.w;
#pragma unroll
    for (int m = 1; m < 64; m <<= 1) {
        s += __shfl_xor(s, m);
        q += __shfl_xor(q, m);
    }
    __shared__ float red[8];
    const int wv = t >> 6, ln = t & 63;
    if (ln == 0) {
        red[wv] = s;
        red[4 + wv] = q;
    }
    __syncthreads();
    s = red[0] + red[1] + red[2] + red[3];
    q = red[4] + red[5] + red[6] + red[7];
    const float mu = s * (1.f / DD);
    const float var = q * (1.f / DD) - mu * mu;
    const float rstd = rsqrtf(var + 1e-5f);
    const float4 gg = ((const float4*)g)[t];
    const float4 bb = ((const float4*)b)[t];
    float4 o;
    o.x = (v.x - mu) * rstd * gg.x + bb.x;
    o.y = (v.y - mu) * rstd * gg.y + bb.y;
    o.z = (v.z - mu) * rstd * gg.z + bb.z;
    o.w = (v.w - mu) * rstd * gg.w + bb.w;
    ((float4*)(of + (size_t)row * DD))[t] = o;
    if (WB) {
        u16x4 u;
        u[0] = f2bf(o.x); u[1] = f2bf(o.y); u[2] = f2bf(o.z); u[3] = f2bf(o.w);
        *(u16x4*)(ob + (size_t)row * DD + t * 4) = u;
    }
}

// ---------------- launch ----------------
extern "C" void kernel_launch(void* const* d_in, const int* in_sizes, int n_in,
                              void* d_out, int out_size, void* d_ws, size_t ws_size,
                              hipStream_t stream) {
    const float* x   = (const float*)d_in[0];
    const float* Wq  = (const float*)d_in[1];
    const float* bq  = (const float*)d_in[2];
    const float* Wk  = (const float*)d_in[3];
    const float* bk  = (const float*)d_in[4];
    const float* Wv  = (const float*)d_in[5];
    const float* bv  = (const float*)d_in[6];
    const float* Wo  = (const float*)d_in[7];
    const float* bo  = (const float*)d_in[8];
    const float* g1  = (const float*)d_in[9];
    const float* be1 = (const float*)d_in[10];
    const float* W1  = (const float*)d_in[11];
    const float* b1  = (const float*)d_in[12];
    const float* W2  = (const float*)d_in[13];
    const float* b2  = (const float*)d_in[14];
    const float* g2  = (const float*)d_in[15];
    const float* be2 = (const float*)d_in[16];
    float* out = (float*)d_out;

    char* ws = (char*)d_ws;
    u16*   xb    = (u16*)(ws + 0);           // 16 MB   (reused as ctx)
    u16*   wqkvt = (u16*)(ws + 16777216);    // 6 MB
    u16*   wot   = (u16*)(ws + 23068672);    // 2 MB
    u16*   w1t   = (u16*)(ws + 25165824);    // 4 MB
    u16*   w2t   = (u16*)(ws + 29360128);    // 4 MB
    float* bqkv  = (float*)(ws + 33554432);  // 12 KB
    u16*   qkb   = (u16*)(ws + 33566720);    // 32 MB Q,K  (region reused as h: 48MB total)
    u16*   vtb   = qkb + (size_t)2 * BB * HH * TT * HD;  // 16 MB Vt
    float* y1    = (float*)(ws + 83898368);  // 32 MB  (reused as y2)
    float* x1f   = (float*)(ws + 117452800); // 32 MB
    u16*   x1b   = (u16*)(ws + 151007232);   // 16 MB
    u16*   ctx   = xb;
    u16*   hbuf  = qkb;
    float* y2    = y1;

    const int M = BB * TT;  // 8192

    // conversions
    convert_x<<<dim3((M * DD / 8 + 255) / 256), 256, 0, stream>>>(x, xb, M * DD / 8);
    qkv_transpose<<<dim3(2, 32, 48), 256, 0, stream>>>(Wq, Wk, Wv, wqkvt);
    transpose_conv<<<dim3(32, 32), 256, 0, stream>>>(Wo, wot, DD, DD);
    transpose_conv<<<dim3(64, 32), 256, 0, stream>>>(W1, w1t, DD, FF);
    transpose_conv<<<dim3(32, 64), 256, 0, stream>>>(W2, w2t, FF, DD);
    pack_bias<<<dim3(12), 256, 0, stream>>>(bq, bk, bv, bqkv);

    // QKV projection (Q pre-scaled, V stored transposed)
    gemm_bt<0><<<dim3(3 * DD / GBN, M / GBM), 256, 0, stream>>>(xb, wqkvt, bqkv, nullptr, qkb, vtb, M, 3 * DD, DD);
    // attention
    attn_kernel<<<dim3(TT / 128, BB * HH), 256, 0, stream>>>(qkb, vtb, ctx);
    // output projection + bias + residual(x)
    gemm_bt<1><<<dim3(DD / GBN, M / GBM), 256, 0, stream>>>(ctx, wot, bo, x, y1, nullptr, M, DD, DD);
    // LN1 -> x1f (f32) + x1b (bf16)
    ln_kernel<true><<<dim3(M), 256, 0, stream>>>(y1, g1, be1, x1f, x1b);
    // FFN1 (relu)
    gemm_bt<2><<<dim3(FF / GBN, M / GBM), 256, 0, stream>>>(x1b, w1t, b1, nullptr, hbuf, nullptr, M, FF, DD);
    // FFN2 + bias + residual(x1f)
    gemm_bt<3><<<dim3(DD / GBN, M / GBM), 256, 0, stream>>>(hbuf, w2t, b2, x1f, y2, nullptr, M, DD, FF);
    // LN2 -> out
    ln_kernel<false><<<dim3(M), 256, 0, stream>>>(y2, g2, be2, out, nullptr);
}